// Round 1
// 946.481 us; speedup vs baseline: 1.1100x; 1.1100x over previous
//
#include <hip/hip_runtime.h>
#include <stdint.h>

typedef __attribute__((ext_vector_type(8))) short short8;
typedef __attribute__((ext_vector_type(4))) float f32x4;
typedef __attribute__((ext_vector_type(4))) unsigned short u16x4;

__device__ __forceinline__ unsigned short f2bf(float x){
  union { float f; unsigned int u; } v; v.f = x;
  unsigned int r = v.u + 0x7fffu + ((v.u >> 16) & 1u);
  return (unsigned short)(r >> 16);
}

__device__ __forceinline__ f32x4 mfma16(short8 a, short8 b, f32x4 c){
  return __builtin_amdgcn_mfma_f32_16x16x32_bf16(a, b, c, 0, 0, 0);
}

__device__ __forceinline__ void async16(const void* g, void* l){
  __builtin_amdgcn_global_load_lds(
      (__attribute__((address_space(1))) void*)g,
      (__attribute__((address_space(3))) void*)l, 16, 0, 0);
}

#if __has_builtin(__builtin_amdgcn_exp2f)
__device__ __forceinline__ float exp2_fast(float x){ return __builtin_amdgcn_exp2f(x); }
#else
__device__ __forceinline__ float exp2_fast(float x){ return __expf(x * 0.69314718f); }
#endif

__device__ __forceinline__ u16x4 cvt4(float4 x){
  u16x4 r; r.x = f2bf(x.x); r.y = f2bf(x.y); r.z = f2bf(x.z); r.w = f2bf(x.w);
  return r;
}

// ---------- fused elementwise prep: all bf16 conversions in one launch ----------
// regions (float4 units): [0,524288) hs+pos->Aq ; [524288,2621440) kv(,+kvpos)->Av,Ak ;
// then 4x 262144 for Wq,Wk,Wv,Wo.
__global__ __launch_bounds__(256) void k_prep_all(
    const float4* __restrict__ hs, const float4* __restrict__ pos,
    const float4* __restrict__ kv, const float4* __restrict__ kvpos,
    const float4* __restrict__ Wq, const float4* __restrict__ Wk,
    const float4* __restrict__ Wv, const float4* __restrict__ Wo,
    u16x4* __restrict__ Aq, u16x4* __restrict__ Ak, u16x4* __restrict__ Av,
    u16x4* __restrict__ Wqb, u16x4* __restrict__ Wkb,
    u16x4* __restrict__ Wvb, u16x4* __restrict__ Wob)
{
  int i = blockIdx.x * 256 + threadIdx.x;
  if (i < 524288){
    float4 a = hs[i], b = pos[i];
    a.x += b.x; a.y += b.y; a.z += b.z; a.w += b.w;
    Aq[i] = cvt4(a);
  } else if (i < 2621440){
    int j = i - 524288;
    float4 a = kv[j], b = kvpos[j];
    Av[j] = cvt4(a);
    a.x += b.x; a.y += b.y; a.z += b.z; a.w += b.w;
    Ak[j] = cvt4(a);
  } else if (i < 2883584){
    int j = i - 2621440; Wqb[j] = cvt4(Wq[j]);
  } else if (i < 3145728){
    int j = i - 2883584; Wkb[j] = cvt4(Wk[j]);
  } else if (i < 3407872){
    int j = i - 3145728; Wvb[j] = cvt4(Wv[j]);
  } else {
    int j = i - 3407872; Wob[j] = cvt4(Wo[j]);
  }
}

// ---------- GEMM: C[m][n] = sum_k A[m][k]*W[n][k] (+bias)*scale ----------
// K = 1024 fixed. 128x128 tile, BK=32, 256 threads (2x2 waves of 64x64).
// MODE 0: bf16 out [B*H, seq, 64], rows rr = seq*2+b (Q/K).
// MODE 1: fp32 out [T, B, D], rows rr = b*1024+t (final output).
// MODE 2: bf16 V^T out [B*H, 64, 4096], rows rr = seq*2+b (V, transposed store).
template<int MODE>
__global__ __launch_bounds__(256,2) void k_gemm(const unsigned short* __restrict__ A,
    const unsigned short* __restrict__ W, const float* __restrict__ bias,
    void* __restrict__ outp, int M, float scale)
{
  __shared__ unsigned short lA[128*32];
  __shared__ unsigned short lB[128*32];
  const int tid = threadIdx.x, lane = tid & 63, w = tid >> 6;
  const int quad = lane >> 4, m16 = lane & 15;
  const int wm = w & 1, wn = w >> 1;
  const int row0 = blockIdx.x * 128, col0 = blockIdx.y * 128;
  const int g0 = w*64 + lane, g1 = (w+4)*64 + lane;
  const int r0g = g0 & 127, q0g = g0 >> 7;
  const int r1g = g1 & 127, q1g = g1 >> 7;
  const unsigned short* Ab = A + (size_t)row0 * 1024;
  const unsigned short* Bb = W + (size_t)col0 * 1024;
  f32x4 acc[4][4] = {};
  for (int k0 = 0; k0 < 1024; k0 += 32){
    async16(Ab + (size_t)r0g*1024 + k0 + q0g*8, &lA[w*512]);
    async16(Ab + (size_t)r1g*1024 + k0 + q1g*8, &lA[(w+4)*512]);
    async16(Bb + (size_t)r0g*1024 + k0 + q0g*8, &lB[w*512]);
    async16(Bb + (size_t)r1g*1024 + k0 + q1g*8, &lB[(w+4)*512]);
    __syncthreads();
    short8 af[4], bfr[4];
    #pragma unroll
    for (int mt = 0; mt < 4; ++mt)
      af[mt] = *(const short8*)&lA[(quad*128 + wm*64 + mt*16 + m16)*8];
    #pragma unroll
    for (int nt = 0; nt < 4; ++nt)
      bfr[nt] = *(const short8*)&lB[(quad*128 + wn*64 + nt*16 + m16)*8];
    #pragma unroll
    for (int mt = 0; mt < 4; ++mt)
      #pragma unroll
      for (int nt = 0; nt < 4; ++nt)
        acc[mt][nt] = mfma16(af[mt], bfr[nt], acc[mt][nt]);
    __syncthreads();
  }
  if (MODE == 0){
    unsigned short* out16 = (unsigned short*)outp;
    const int SEQ = M >> 1;
    #pragma unroll
    for (int nt = 0; nt < 4; ++nt){
      const int n = col0 + wn*64 + nt*16 + m16;
      const float bvv = bias[n];
      const int h = n >> 6, d = n & 63;
      #pragma unroll
      for (int mt = 0; mt < 4; ++mt){
        const int rbase = row0 + wm*64 + mt*16 + quad*4;
        #pragma unroll
        for (int r = 0; r < 4; ++r){
          const int rr = rbase + r;
          const int seq = rr >> 1, bb = rr & 1;
          const float vv = (acc[mt][nt][r] + bvv) * scale;
          out16[(((size_t)(bb*16 + h) * SEQ + seq) << 6) + d] = f2bf(vv);
        }
      }
    }
  } else if (MODE == 1){
    float* outf = (float*)outp;
    #pragma unroll
    for (int nt = 0; nt < 4; ++nt){
      const int n = col0 + wn*64 + nt*16 + m16;
      const float bvv = bias[n];
      #pragma unroll
      for (int mt = 0; mt < 4; ++mt){
        const int rbase = row0 + wm*64 + mt*16 + quad*4;
        #pragma unroll
        for (int r = 0; r < 4; ++r){
          const int rr = rbase + r;
          const int tt = rr & 1023, bb = rr >> 10;
          outf[(((size_t)tt*2 + bb) << 10) + n] = acc[mt][nt][r] + bvv;
        }
      }
    }
  } else {
    // V^T: out[(bb*16+h)*64 + d][seq], dims [32][64][4096]
    unsigned short* out16 = (unsigned short*)outp;
    #pragma unroll
    for (int nt = 0; nt < 4; ++nt){
      const int n = col0 + wn*64 + nt*16 + m16;
      const float bvv = bias[n];
      const int h = n >> 6, d = n & 63;
      #pragma unroll
      for (int mt = 0; mt < 4; ++mt){
        const int rbase = row0 + wm*64 + mt*16 + quad*4;
        #pragma unroll
        for (int r = 0; r < 4; ++r){
          const int rr = rbase + r;
          const int seq = rr >> 1, bb = rr & 1;
          out16[(((size_t)((bb*16 + h)*64 + d)) << 12) + seq] = f2bf(acc[mt][nt][r] + bvv);
        }
      }
    }
  }
}

// ---------- flash attention v2 ----------
// grid 512 = BH(32) x Ttiles(16); 4 waves x 16 Q-rows; S tiles of 64.
// K/V tiles staged ONCE per block into double-buffered XOR-swizzled LDS via
// global_load_lds (cuts K/V L2 traffic 4x vs per-wave register staging).
// Softmax in exp2 domain: log2(e) folded into Q scale + mask FMA.
__global__ __launch_bounds__(256,2) void k_flash(const unsigned short* __restrict__ Qp,
    const unsigned short* __restrict__ Kp, const unsigned short* __restrict__ VTp,
    const float* __restrict__ mask, unsigned short* __restrict__ ctx)
{
  __shared__ unsigned short lK0[4096], lK1[4096];   // 8 KB each: [64 s][8 chunk16B] swizzled
  __shared__ unsigned short lV0[4096], lV1[4096];   // 8 KB each: [64 d][8 chunk16B] swizzled
  __shared__ unsigned short pl[4096];               // per-wave 2 KB P staging
  const int tid = threadIdx.x, lane = tid & 63, w = tid >> 6;
  const int quad = lane >> 4, m16 = lane & 15;
  const int bh = blockIdx.x >> 4;
  const int t0 = ((blockIdx.x & 15) << 6) + w*16;
  short8 qa0, qa1;
  {
    const unsigned short* qp = Qp + (((size_t)bh*1024 + t0 + m16) << 6) + quad*8;
    qa0 = *(const short8*)qp;
    qa1 = *(const short8*)(qp + 32);
  }
  const unsigned short* Kbh = Kp + ((size_t)bh << 18);   // row seq: 64 shorts (128B)
  const unsigned short* Vbh = VTp + ((size_t)bh << 18);  // row d: 4096 shorts (8KB)
  const float* mb = mask + ((size_t)bh*1024 + t0 + quad*4) * 4096 + m16;
  unsigned short* pw = &pl[w*1024];
  const unsigned short* prd0 = &pl[w*1024 + (quad*16 + (m16 ^ quad))*8];
  const unsigned short* prd1 = &pl[w*1024 + ((quad+4)*16 + (m16 ^ (quad+4)))*8];

  // staging: thread covers 16B chunk g=tid (rows 0..31) and g=256+tid (rows 32..63)
  // LDS[r][k] = global[r][k ^ (r&7)]  (source pre-swizzled, dest linear)
  const int sr = tid >> 3;                    // row 0..31 (+32 for 2nd call)
  const int sk = (tid & 7) ^ (sr & 7);        // pre-swizzled source chunk
  // read swizzle: want global chunk quad / quad+4 of row with (row&7)==(m16&7)
  const int swzlo = quad ^ (m16 & 7);
  const int swzhi = swzlo ^ 4;

  f32x4 Oa[4] = {};
  float mrow[4], lrow[4];
  #pragma unroll
  for (int r = 0; r < 4; ++r){ mrow[r] = -1e30f; lrow[r] = 0.f; }
  const f32x4 zero4 = {0.f, 0.f, 0.f, 0.f};
  float mA[16], mB[16];

  auto STAGE = [&](int s0, unsigned short* dK, unsigned short* dV){
    async16(Kbh + (size_t)(s0 + sr)*64 + sk*8,        dK + w*512);
    async16(Kbh + (size_t)(s0 + 32 + sr)*64 + sk*8,   dK + 2048 + w*512);
    async16(Vbh + (size_t)sr*4096 + s0 + sk*8,        dV + w*512);
    async16(Vbh + (size_t)(32 + sr)*4096 + s0 + sk*8, dV + 2048 + w*512);
  };
  auto LM = [&](int s0, float* mf){
    const float* mp = mb + s0;
    #pragma unroll
    for (int c = 0; c < 4; ++c)
      #pragma unroll
      for (int r = 0; r < 4; ++r)
        mf[c*4+r] = __builtin_nontemporal_load(mp + (size_t)r*4096 + c*16);
  };
  auto PROC = [&](const unsigned short* Kt, const unsigned short* Vt, const float* mf){
    short8 kf[8];
    #pragma unroll
    for (int c = 0; c < 4; ++c){
      const unsigned short* kp = Kt + (c*128 + m16*8)*8;
      kf[2*c]   = *(const short8*)(kp + swzlo*8);
      kf[2*c+1] = *(const short8*)(kp + swzhi*8);
    }
    short8 vf[8];
    #pragma unroll
    for (int cn = 0; cn < 4; ++cn){
      const unsigned short* vp = Vt + (cn*128 + m16*8)*8;
      vf[2*cn]   = *(const short8*)(vp + swzlo*8);
      vf[2*cn+1] = *(const short8*)(vp + swzhi*8);
    }
    f32x4 sc[4];
    #pragma unroll
    for (int c = 0; c < 4; ++c){
      f32x4 z = mfma16(qa0, kf[2*c], zero4);
      sc[c] = mfma16(qa1, kf[2*c+1], z);
    }
    // mask add in log2 domain (scores already carry log2e via Q scale)
    #pragma unroll
    for (int c = 0; c < 4; ++c)
      #pragma unroll
      for (int r = 0; r < 4; ++r)
        sc[c][r] = fmaf(mf[c*4+r], 1.44269504f, sc[c][r]);
    float rmax[4];
    #pragma unroll
    for (int r = 0; r < 4; ++r)
      rmax[r] = fmaxf(fmaxf(sc[0][r], sc[1][r]), fmaxf(sc[2][r], sc[3][r]));
    #pragma unroll
    for (int off = 1; off <= 8; off <<= 1)
      #pragma unroll
      for (int r = 0; r < 4; ++r)
        rmax[r] = fmaxf(rmax[r], __shfl_xor(rmax[r], off, 64));
    float al[4], rsum[4];
    #pragma unroll
    for (int r = 0; r < 4; ++r){
      float mn = fmaxf(mrow[r], rmax[r]);
      al[r] = exp2_fast(mrow[r] - mn);
      mrow[r] = mn;
      rsum[r] = 0.f;
    }
    #pragma unroll
    for (int c = 0; c < 4; ++c)
      #pragma unroll
      for (int r = 0; r < 4; ++r){
        float p = exp2_fast(sc[c][r] - mrow[r]);
        sc[c][r] = p;
        rsum[r] += p;
      }
    #pragma unroll
    for (int off = 1; off <= 8; off <<= 1)
      #pragma unroll
      for (int r = 0; r < 4; ++r)
        rsum[r] += __shfl_xor(rsum[r], off, 64);
    #pragma unroll
    for (int r = 0; r < 4; ++r)
      lrow[r] = lrow[r]*al[r] + rsum[r];
    #pragma unroll
    for (int cn = 0; cn < 4; ++cn)
      #pragma unroll
      for (int r = 0; r < 4; ++r)
        Oa[cn][r] *= al[r];
    // P -> LDS (XOR-swizzled granules)
    #pragma unroll
    for (int c = 0; c < 4; ++c){
      const int kch = c*2 + (m16 >> 3);
      #pragma unroll
      for (int r = 0; r < 4; ++r){
        const int row = quad*4 + r;
        pw[(kch*16 + (row ^ kch))*8 + (m16 & 7)] = f2bf(sc[c][r]);
      }
    }
    asm volatile("s_waitcnt lgkmcnt(0)" ::: "memory");
    short8 pa0 = *(const short8*)prd0;
    short8 pa1 = *(const short8*)prd1;
    #pragma unroll
    for (int cn = 0; cn < 4; ++cn){
      Oa[cn] = mfma16(pa0, vf[2*cn], Oa[cn]);
      Oa[cn] = mfma16(pa1, vf[2*cn+1], Oa[cn]);
    }
  };

  STAGE(0, lK0, lV0); LM(0, mA);
  asm volatile("s_waitcnt vmcnt(0)" ::: "memory");
  __syncthreads();
  for (int s0 = 0; s0 < 4096; s0 += 128){
    STAGE(s0+64, lK1, lV1); LM(s0+64, mB);
    PROC(lK0, lV0, mA);
    __syncthreads();   // drains vmcnt (stage of buf1 done) + all waves done reading buf0
    if (s0 + 128 < 4096){ STAGE(s0+128, lK0, lV0); LM(s0+128, mA); }
    PROC(lK1, lV1, mB);
    __syncthreads();
  }

  const int b = bh >> 4, h = bh & 15;
  unsigned short* op = ctx + (((size_t)b*1024 + t0 + quad*4) << 10) + h*64 + m16;
  #pragma unroll
  for (int r = 0; r < 4; ++r){
    float inv = 1.f / lrow[r];
    #pragma unroll
    for (int cn = 0; cn < 4; ++cn)
      op[((size_t)r << 10) + cn*16] = f2bf(Oa[cn][r]*inv);
  }
}

extern "C" void kernel_launch(void* const* d_in, const int* in_sizes, int n_in,
                              void* d_out, int out_size, void* d_ws, size_t ws_size,
                              hipStream_t stream)
{
  (void)in_sizes; (void)n_in; (void)out_size; (void)ws_size;
  const float* hs    = (const float*)d_in[0];
  const float* mask  = (const float*)d_in[1];
  const float* pos   = (const float*)d_in[2];
  const float* kv    = (const float*)d_in[3];
  const float* kvpos = (const float*)d_in[4];
  const float* Wq = (const float*)d_in[5];  const float* biq = (const float*)d_in[6];
  const float* Wk = (const float*)d_in[7];  const float* bik = (const float*)d_in[8];
  const float* Wv = (const float*)d_in[9];  const float* biv = (const float*)d_in[10];
  const float* Wo = (const float*)d_in[11]; const float* bio = (const float*)d_in[12];
  float* out = (float*)d_out;
  char* ws = (char*)d_ws;
  unsigned short* Aq  = (unsigned short*)(ws + ( 0ull << 20));  // 4 MB
  unsigned short* Ak  = (unsigned short*)(ws + ( 4ull << 20));  // 16 MB
  unsigned short* Av  = (unsigned short*)(ws + (20ull << 20));  // 16 MB
  unsigned short* Wqb = (unsigned short*)(ws + (36ull << 20));  // 2 MB
  unsigned short* Wkb = (unsigned short*)(ws + (38ull << 20));  // 2 MB
  unsigned short* Wvb = (unsigned short*)(ws + (40ull << 20));  // 2 MB
  unsigned short* Wob = (unsigned short*)(ws + (42ull << 20));  // 2 MB
  unsigned short* Qb  = (unsigned short*)(ws + (44ull << 20));  // 4 MB
  unsigned short* Kb  = (unsigned short*)(ws + (48ull << 20));  // 16 MB
  unsigned short* VTb = (unsigned short*)(ws + (64ull << 20));  // 16 MB (end 80 MB)
  unsigned short* ctx = (unsigned short*)(ws + (36ull << 20));  // overlay Wqb/Wkb (dead)

  k_prep_all<<<dim3(14336), dim3(256), 0, stream>>>(
      (const float4*)hs, (const float4*)pos, (const float4*)kv, (const float4*)kvpos,
      (const float4*)Wq, (const float4*)Wk, (const float4*)Wv, (const float4*)Wo,
      (u16x4*)Aq, (u16x4*)Ak, (u16x4*)Av,
      (u16x4*)Wqb, (u16x4*)Wkb, (u16x4*)Wvb, (u16x4*)Wob);

  // Q scale carries softmax's log2(e): 0.125 * 1.44269504
  k_gemm<0><<<dim3(16, 8), dim3(256), 0, stream>>>(Aq, Wqb, biq, Qb, 2048, 0.18033688f);
  k_gemm<0><<<dim3(64, 8), dim3(256), 0, stream>>>(Ak, Wkb, bik, Kb, 8192, 1.0f);
  k_gemm<2><<<dim3(64, 8), dim3(256), 0, stream>>>(Av, Wvb, biv, VTb, 8192, 1.0f);
  k_flash<<<dim3(512), dim3(256), 0, stream>>>(Qb, Kb, VTb, mask, ctx);
  k_gemm<1><<<dim3(16, 8), dim3(256), 0, stream>>>(ctx, Wob, bio, out, 2048, 1.0f);
}